// Round 8
// baseline (514.285 us; speedup 1.0000x reference)
//
#include <hip/hip_runtime.h>

#define N_TOT 211072   // B*V = 32*6596
#define V_MESH 6596
#define E_TOT 633216   // 3*N
#define CAP 32
#define KP 184         // feats row width in bf16 (368B; MFMA reads cols 0..159)
#define KSTEPS 5       // 5*32 = 160 >= 131

typedef __attribute__((ext_vector_type(8))) short bf16x8;
typedef __attribute__((ext_vector_type(4))) float f32x4;

__constant__ float c_LIM[14] = {0.04f,0.06f,0.04f,0.04f,0.02f,0.02f,0.04f,0.04f,
                                0.03f,0.03f,0.02f,0.02f,0.01f,0.01f};

__device__ __forceinline__ unsigned f2bf(float f) {   // RNE f32->bf16
    unsigned x = __float_as_uint(f);
    return (x + 0x7fffu + ((x >> 16) & 1u)) >> 16;
}
__device__ __forceinline__ float bflo(unsigned u) { return __uint_as_float(u << 16); }
__device__ __forceinline__ float bfhi(unsigned u) { return __uint_as_float(u & 0xffff0000u); }
// truncating pack: low16 = hi16(a0), high16 = hi16(a1)  (one v_perm_b32)
__device__ __forceinline__ unsigned pk_trunc(float a0, float a1) {
    return __builtin_amdgcn_perm(__float_as_uint(a1), __float_as_uint(a0), 0x07060302u);
}

// ---------------- adjacency build ----------------
__global__ __launch_bounds__(256) void fill_adj_kernel(const int* __restrict__ edges,
                                                       int* __restrict__ cnt,
                                                       int* __restrict__ adj) {
    int e = blockIdx.x * 256 + threadIdx.x;
    if (e >= E_TOT) return;
    int2 ed = ((const int2*)edges)[e];
    int p0 = atomicAdd(&cnt[ed.x], 1);
    if (p0 < CAP) adj[(size_t)ed.x * CAP + p0] = ed.y;
    int p1 = atomicAdd(&cnt[ed.y], 1);
    if (p1 < CAP) adj[(size_t)ed.y * CAP + p1] = ed.x;
}

// ---------------- pad adjacency rows with sentinel up to 8-multiple ----------------
__global__ __launch_bounds__(256) void pad_adj_kernel(const int* __restrict__ cnt,
                                                      int* __restrict__ adj) {
    int i = blockIdx.x * 256 + threadIdx.x;
    if (i >= N_TOT) return;
    int deg = cnt[i]; if (deg > CAP) deg = CAP;
    int end = (deg <= 8) ? 8 : ((deg + 7) & ~7);
    if (end > CAP) end = CAP;
    for (int k = deg; k < end; ++k) adj[(size_t)i * CAP + k] = N_TOT;
}

// ---------------- weight conversion: Wt[256][184] bf16 (transposed, zero-padded), bb[256] ----------------
__global__ __launch_bounds__(256) void conv_w_kernel(const float* __restrict__ w0,
                                                     const float* __restrict__ b0,
                                                     const float* __restrict__ w1,
                                                     const float* __restrict__ b1,
                                                     short* __restrict__ Wt,
                                                     float* __restrict__ bb) {
    int c = blockIdx.x;          // 0..255 output col
    int k = threadIdx.x;         // 0..255
    const float* w = (c < 128) ? w0 : w1;
    int cc = c & 127;
    if (k < KP) {
        unsigned val = (k < 131) ? f2bf(w[(size_t)k * 128 + cc]) : 0u;
        Wt[(size_t)c * KP + k] = (short)val;
    }
    if (k == 0) bb[c] = (c < 128) ? b0[cc] : b1[cc];
}

// ---------------- layer 0 matmul (feats = normals, d=3) -> xc interleaved bf16 ----------------
__global__ __launch_bounds__(256) void mm3_kernel(const float* __restrict__ normals,
                                                  const float* __restrict__ w0,
                                                  const float* __restrict__ b0,
                                                  const float* __restrict__ w1,
                                                  const float* __restrict__ b1,
                                                  unsigned* __restrict__ xc) { // [N+1][128] dwords
    __shared__ float nL[32][3];
    int t = threadIdx.x;
    int row0 = blockIdx.x * 32;
    if (t < 96) {
        int r = t / 3, k = t - r * 3;
        nL[r][k] = normals[(size_t)(row0 + r) * 3 + k];
    }
    __syncthreads();
    int m  = (t >> 6) & 1;   // 0 -> x0 half, 1 -> x1 half
    int rh = t >> 7;
    int c2 = t & 63;         // column pair 2*c2, 2*c2+1
    const float* w = m ? w1 : w0;
    const float* b = m ? b1 : b0;
    float wA0 = w[0*128 + 2*c2],     wA1 = w[1*128 + 2*c2],     wA2 = w[2*128 + 2*c2];
    float wB0 = w[0*128 + 2*c2 + 1], wB1 = w[1*128 + 2*c2 + 1], wB2 = w[2*128 + 2*c2 + 1];
    float bA = b[2*c2], bB = b[2*c2 + 1];
    #pragma unroll
    for (int r = 0; r < 16; ++r) {
        int lr = rh * 16 + r;
        float vA = bA + nL[lr][0]*wA0 + nL[lr][1]*wA1 + nL[lr][2]*wA2;
        float vB = bB + nL[lr][0]*wB0 + nL[lr][1]*wB1 + nL[lr][2]*wB2;
        xc[(size_t)(row0 + lr) * 128 + m * 64 + c2] = f2bf(vA) | (f2bf(vB) << 16);
    }
}

// ---------------- fused: pair-gather (dwordx2, 2 neighbors/load) + relu -> LDS -> MFMA -> xc' ----
// 1024 threads = 16 waves; wave w owns one node. Wave splits into two 32-lane halves:
// lane (half, c) owns bf16 cols 4c..4c+3; half h loads neighbor 2k+h. One round of
// 4 dwordx2 loads covers 8 neighbors. Sentinel N_TOT -> zero row.
__global__ __launch_bounds__(1024, 8) void fused_kernel(const unsigned* __restrict__ xc_in, // [N+1][128]
                                                        const float* __restrict__ normals,
                                                        const int* __restrict__ cnt,
                                                        const int* __restrict__ adj,
                                                        const short* __restrict__ Wt,      // [256][184]
                                                        const float* __restrict__ bb,      // [256]
                                                        unsigned* __restrict__ xc_out) {   // [N+1][128]
    __shared__ short tileA[16 * KP];     // 5888 B gathered feats
    __shared__ short tileC[16 * 256];    // 8192 B output staging (pair-packed, swizzled)
    int tid  = threadIdx.x;
    int w    = tid >> 6;
    int lane = tid & 63;
    int half = lane >> 5;
    int c    = lane & 31;
    int g    = lane >> 4;
    int ln   = lane & 15;
    int row0 = blockIdx.x * 16;
    int i    = row0 + w;

    // ---- early independent loads ----
    int deg0 = cnt[i];
    int jv = (lane < CAP) ? adj[(size_t)i * CAP + lane] : (int)N_TOT;
    uint2 selfu = *(const uint2*)(xc_in + (size_t)i * 128 + 2 * c);   // x0 dwords 2c,2c+1
    float nv = (lane < 3) ? normals[(size_t)i * 3 + lane] : 0.f;

    // ---- round 0: 4 dwordx2 loads cover neighbors 0..7 ----
    const unsigned* gbase = xc_in + 64 + 2 * c;   // + j*128
    uint2 u[4];
    #pragma unroll
    for (int q = 0; q < 4; ++q) {
        int j = __shfl(jv, 2 * q + half);
        u[q] = *(const uint2*)(gbase + (size_t)j * 128);
    }
    float a0 = 0.f, a1 = 0.f, a2 = 0.f, a3 = 0.f;
    #pragma unroll
    for (int q = 0; q < 4; ++q) {
        a0 += bflo(u[q].x); a1 += bfhi(u[q].x);
        a2 += bflo(u[q].y); a3 += bfhi(u[q].y);
    }
    // ---- extra rounds (deg > 8, ~15% of nodes) ----
    int deg = (deg0 > CAP) ? CAP : deg0;
    deg = __builtin_amdgcn_readfirstlane(deg);
    for (int bq = 8; bq < deg; bq += 8) {
        uint2 v[4];
        #pragma unroll
        for (int q = 0; q < 4; ++q) {
            int j = __shfl(jv, bq + 2 * q + half);
            v[q] = *(const uint2*)(gbase + (size_t)j * 128);
        }
        #pragma unroll
        for (int q = 0; q < 4; ++q) {
            a0 += bflo(v[q].x); a1 += bfhi(v[q].x);
            a2 += bflo(v[q].y); a3 += bfhi(v[q].y);
        }
    }
    // ---- merge halves, add self, relu ----
    a0 += __shfl_xor(a0, 32);
    a1 += __shfl_xor(a1, 32);
    a2 += __shfl_xor(a2, 32);
    a3 += __shfl_xor(a3, 32);
    a0 = fmaxf(a0 + bflo(selfu.x), 0.f);
    a1 = fmaxf(a1 + bfhi(selfu.x), 0.f);
    a2 = fmaxf(a2 + bflo(selfu.y), 0.f);
    a3 = fmaxf(a3 + bfhi(selfu.y), 0.f);

    // ---- write tile row: half0 -> h dwords 0..63, half1 -> normals dwords 64..79 ----
    unsigned* tA32 = (unsigned*)tileA;
    unsigned nb = f2bf(nv);
    unsigned nb0 = __shfl((int)nb, 0), nb1 = __shfl((int)nb, 1), nb2 = __shfl((int)nb, 2);
    if (half == 0) {
        uint2 pk;
        pk.x = pk_trunc(a0, a1);
        pk.y = pk_trunc(a2, a3);
        *(uint2*)(tA32 + w * (KP / 2) + 2 * c) = pk;
    } else if (c < 16) {
        unsigned v = (c == 0) ? (nb0 | (nb1 << 16)) : (c == 1) ? nb2 : 0u;
        tA32[w * (KP / 2) + 64 + c] = v;
    }
    __syncthreads();

    // ---- MFMA: wave w computes 16 rows x 16 cols (col block w*16) over K=160 ----
    int cb = w * 16;
    float bv = bb[cb + ln];
    f32x4 acc = {bv, bv, bv, bv};
    #pragma unroll
    for (int kk = 0; kk < KSTEPS; ++kk) {
        bf16x8 bf = *(const bf16x8*)(Wt + (size_t)(cb + ln) * KP + kk * 32 + g * 8);
        bf16x8 af = *(const bf16x8*)(tileA + ln * KP + kk * 32 + g * 8);
        acc = __builtin_amdgcn_mfma_f32_16x16x32_bf16(af, bf, acc, 0, 0, 0);
    }
    // pair-pack cols via shfl, dword stores, XOR-swizzle by lane-group -> conflict-free
    #pragma unroll
    for (int j = 0; j < 4; ++j) {
        float po = __shfl_xor(acc[j], 1);
        if (!(ln & 1)) {
            unsigned pk = f2bf(acc[j]) | (f2bf(po) << 16);
            int dd = w * 8 + (ln >> 1);          // true dword within row
            int row = g * 4 + j;
            ((unsigned*)tileC)[row * 128 + (dd ^ (g << 3))] = pk;
        }
    }
    __syncthreads();

    // ---- coalesced row writeback (inverse swizzle; key = row's writer-group) ----
    int key = (w >> 2) << 3;
    ushort4 v4 = *(const ushort4*)&((unsigned*)tileC)[w * 128 + ((2 * lane) ^ key)];
    ((ushort4*)(xc_out + (size_t)(row0 + w) * 128))[lane] = v4;
}

// ---------------- final: pair-gather + relu -> h (f32) + deform + vertex update ----------------
__global__ __launch_bounds__(256) void final_fused_kernel(const unsigned* __restrict__ xc_in,
                                                          const int* __restrict__ cnt,
                                                          const int* __restrict__ adj,
                                                          const float* __restrict__ normals,
                                                          const float* __restrict__ verts,
                                                          const float* __restrict__ anchor_v,
                                                          const int* __restrict__ part_id,
                                                          const float* __restrict__ w_off,
                                                          const float* __restrict__ b_off,
                                                          float* __restrict__ hout,
                                                          float* __restrict__ out_verts) {
    __shared__ float wo[131 * 3];
    for (int t = threadIdx.x; t < 131 * 3; t += 256) wo[t] = w_off[t];
    __syncthreads();
    int tid  = threadIdx.x;
    int w    = tid >> 6;
    int lane = tid & 63;
    int half = lane >> 5;
    int c    = lane & 31;
    int i    = blockIdx.x * 4 + w;

    int deg0 = cnt[i];
    int jv = (lane < CAP) ? adj[(size_t)i * CAP + lane] : (int)N_TOT;
    uint2 selfu = *(const uint2*)(xc_in + (size_t)i * 128 + 2 * c);

    const unsigned* gbase = xc_in + 64 + 2 * c;
    uint2 u[4];
    #pragma unroll
    for (int q = 0; q < 4; ++q) {
        int j = __shfl(jv, 2 * q + half);
        u[q] = *(const uint2*)(gbase + (size_t)j * 128);
    }
    float a0 = 0.f, a1 = 0.f, a2 = 0.f, a3 = 0.f;
    #pragma unroll
    for (int q = 0; q < 4; ++q) {
        a0 += bflo(u[q].x); a1 += bfhi(u[q].x);
        a2 += bflo(u[q].y); a3 += bfhi(u[q].y);
    }
    int deg = (deg0 > CAP) ? CAP : deg0;
    deg = __builtin_amdgcn_readfirstlane(deg);
    for (int bq = 8; bq < deg; bq += 8) {
        uint2 v[4];
        #pragma unroll
        for (int q = 0; q < 4; ++q) {
            int j = __shfl(jv, bq + 2 * q + half);
            v[q] = *(const uint2*)(gbase + (size_t)j * 128);
        }
        #pragma unroll
        for (int q = 0; q < 4; ++q) {
            a0 += bflo(v[q].x); a1 += bfhi(v[q].x);
            a2 += bflo(v[q].y); a3 += bfhi(v[q].y);
        }
    }
    a0 += __shfl_xor(a0, 32);
    a1 += __shfl_xor(a1, 32);
    a2 += __shfl_xor(a2, 32);
    a3 += __shfl_xor(a3, 32);
    a0 = fmaxf(a0 + bflo(selfu.x), 0.f);
    a1 = fmaxf(a1 + bfhi(selfu.x), 0.f);
    a2 = fmaxf(a2 + bflo(selfu.y), 0.f);
    a3 = fmaxf(a3 + bfhi(selfu.y), 0.f);

    // h store: half0 lanes write float4 -> full 512B row per wave
    if (half == 0) {
        float4 hv; hv.x = a0; hv.y = a1; hv.z = a2; hv.w = a3;
        *(float4*)(hout + (size_t)i * 128 + 4 * c) = hv;
    }

    // offset head: partial dot over this lane's 4 cols, reduce within each 32-lane half
    int c4 = 4 * c;
    float s0 = a0*wo[c4*3+0] + a1*wo[(c4+1)*3+0] + a2*wo[(c4+2)*3+0] + a3*wo[(c4+3)*3+0];
    float s1 = a0*wo[c4*3+1] + a1*wo[(c4+1)*3+1] + a2*wo[(c4+2)*3+1] + a3*wo[(c4+3)*3+1];
    float s2 = a0*wo[c4*3+2] + a1*wo[(c4+1)*3+2] + a2*wo[(c4+2)*3+2] + a3*wo[(c4+3)*3+2];
    #pragma unroll
    for (int d = 1; d < 32; d <<= 1) {
        s0 += __shfl_xor(s0, d);
        s1 += __shfl_xor(s1, d);
        s2 += __shfl_xor(s2, d);
    }
    if (lane < 3) {
        int v = i % V_MESH;
        float n0 = normals[(size_t)i * 3 + 0];
        float n1 = normals[(size_t)i * 3 + 1];
        float n2 = normals[(size_t)i * 3 + 2];
        float s = (lane == 0) ? s0 : (lane == 1) ? s1 : s2;
        s += n0 * wo[128 * 3 + lane] + n1 * wo[129 * 3 + lane] + n2 * wo[130 * 3 + lane];
        s += b_off[lane];
        float dd = tanhf(s);
        float lim = c_LIM[part_id[v]];
        dd = fminf(fmaxf(dd, -lim), lim);
        out_verts[(size_t)i * 3 + lane] =
            verts[(size_t)i * 3 + lane] + dd * anchor_v[(size_t)v * 3 + lane];
    }
}

extern "C" void kernel_launch(void* const* d_in, const int* in_sizes, int n_in,
                              void* d_out, int out_size, void* d_ws, size_t ws_size,
                              hipStream_t stream) {
    const float* verts    = (const float*)d_in[0];
    const float* normals  = (const float*)d_in[1];
    const float* anchor_v = (const float*)d_in[2];
    const int*   edges    = (const int*)d_in[3];
    const int*   part_id  = (const int*)d_in[4];
    const float* w0_0 = (const float*)d_in[5];
    const float* b0_0 = (const float*)d_in[6];
    const float* w1_0 = (const float*)d_in[7];
    const float* b1_0 = (const float*)d_in[8];
    const float* w0_1 = (const float*)d_in[9];
    const float* b0_1 = (const float*)d_in[10];
    const float* w1_1 = (const float*)d_in[11];
    const float* b1_1 = (const float*)d_in[12];
    const float* w0_2 = (const float*)d_in[13];
    const float* b0_2 = (const float*)d_in[14];
    const float* w1_2 = (const float*)d_in[15];
    const float* b1_2 = (const float*)d_in[16];
    const float* w_off = (const float*)d_in[17];
    const float* b_off = (const float*)d_in[18];

    float* out_verts = (float*)d_out;
    float* hout = (float*)d_out + (size_t)3 * N_TOT;   // final h (f32)

    // pair B aliases ALL of d_out (verts+h regions dead until final): [N+1][128] dwords
    unsigned* xcB = (unsigned*)d_out;

    char* p = (char*)d_ws;
    unsigned* xcA = (unsigned*)p;  p += (size_t)(N_TOT + 1) * 128 * 4;
    int*   cnt = (int*)p;          p += (size_t)N_TOT * 4;
    int*   adj = (int*)p;          p += (size_t)N_TOT * CAP * 4;
    short* Wt1 = (short*)p;        p += 256 * KP * 2;
    float* bb1 = (float*)p;        p += 256 * 4;
    short* Wt2 = (short*)p;        p += 256 * KP * 2;
    float* bb2 = (float*)p;

    hipMemsetAsync(cnt, 0, (size_t)N_TOT * 4, stream);
    hipMemsetAsync(xcA + (size_t)N_TOT * 128, 0, 512, stream);   // zero row A
    hipMemsetAsync(xcB + (size_t)N_TOT * 128, 0, 512, stream);   // zero row B
    fill_adj_kernel<<<(E_TOT + 255) / 256, 256, 0, stream>>>(edges, cnt, adj);
    pad_adj_kernel<<<(N_TOT + 255) / 256, 256, 0, stream>>>(cnt, adj);
    conv_w_kernel<<<256, 256, 0, stream>>>(w0_1, b0_1, w1_1, b1_1, Wt1, bb1);
    conv_w_kernel<<<256, 256, 0, stream>>>(w0_2, b0_2, w1_2, b1_2, Wt2, bb2);

    // layer 0
    mm3_kernel<<<N_TOT / 32, 256, 0, stream>>>(normals, w0_0, b0_0, w1_0, b1_0, xcA);
    // layer 1: gather(A) -> GEMM -> B
    fused_kernel<<<N_TOT / 16, 1024, 0, stream>>>(xcA, normals, cnt, adj, Wt1, bb1, xcB);
    // layer 2: gather(B) -> GEMM -> A
    fused_kernel<<<N_TOT / 16, 1024, 0, stream>>>(xcB, normals, cnt, adj, Wt2, bb2, xcA);
    // final: gather(A) -> h + verts (writes overlay dead xcB region)
    final_fused_kernel<<<N_TOT / 4, 256, 0, stream>>>(xcA, cnt, adj, normals, verts,
                                                      anchor_v, part_id, w_off, b_off,
                                                      hout, out_verts);
}

// Round 9
// 501.482 us; speedup vs baseline: 1.0255x; 1.0255x over previous
//
#include <hip/hip_runtime.h>

#define N_TOT 211072   // B*V = 32*6596
#define V_MESH 6596
#define E_TOT 633216   // 3*N
#define CAP 32
#define KP 184         // feats row width in bf16 (368B; MFMA reads cols 0..159)
#define KSTEPS 5       // 5*32 = 160 >= 131

typedef __attribute__((ext_vector_type(8))) short bf16x8;
typedef __attribute__((ext_vector_type(4))) float f32x4;

__constant__ float c_LIM[14] = {0.04f,0.06f,0.04f,0.04f,0.02f,0.02f,0.04f,0.04f,
                                0.03f,0.03f,0.02f,0.02f,0.01f,0.01f};

__device__ __forceinline__ unsigned f2bf(float f) {   // RNE f32->bf16 (host-side style)
    unsigned x = __float_as_uint(f);
    return (x + 0x7fffu + ((x >> 16) & 1u)) >> 16;
}
__device__ __forceinline__ float bflo(unsigned u) { return __uint_as_float(u << 16); }
__device__ __forceinline__ float bfhi(unsigned u) { return __uint_as_float(u & 0xffff0000u); }
// HW packed RNE convert: D = {bf16(lo), bf16(hi)}
__device__ __forceinline__ unsigned cvt_pk_bf16(float lo, float hi) {
    unsigned r;
    asm("v_cvt_pk_bf16_f32 %0, %1, %2" : "=v"(r) : "v"(lo), "v"(hi));
    return r;
}

// ---------------- adjacency build ----------------
__global__ __launch_bounds__(256) void fill_adj_kernel(const int* __restrict__ edges,
                                                       int* __restrict__ cnt,
                                                       int* __restrict__ adj) {
    int e = blockIdx.x * 256 + threadIdx.x;
    if (e >= E_TOT) return;
    int2 ed = ((const int2*)edges)[e];
    int p0 = atomicAdd(&cnt[ed.x], 1);
    if (p0 < CAP) adj[(size_t)ed.x * CAP + p0] = ed.y;
    int p1 = atomicAdd(&cnt[ed.y], 1);
    if (p1 < CAP) adj[(size_t)ed.y * CAP + p1] = ed.x;
}

// ---------------- pad adjacency rows with sentinel up to CAP ----------------
__global__ __launch_bounds__(256) void pad_adj_kernel(const int* __restrict__ cnt,
                                                      int* __restrict__ adj) {
    int i = blockIdx.x * 256 + threadIdx.x;
    if (i >= N_TOT) return;
    int deg = cnt[i]; if (deg > CAP) deg = CAP;
    for (int k = deg; k < CAP; ++k) adj[(size_t)i * CAP + k] = N_TOT;
}

// ---------------- normals -> padded float4 rows (zero row at N_TOT) ----------------
__global__ __launch_bounds__(256) void prep_nrm4_kernel(const float* __restrict__ normals,
                                                        float4* __restrict__ nrm4) {
    int i = blockIdx.x * 256 + threadIdx.x;
    if (i > N_TOT) return;
    float4 v = {0.f, 0.f, 0.f, 0.f};
    if (i < N_TOT) {
        v.x = normals[(size_t)i * 3 + 0];
        v.y = normals[(size_t)i * 3 + 1];
        v.z = normals[(size_t)i * 3 + 2];
    }
    nrm4[i] = v;
}

// ---------------- weight conversion: Wt[256][184] bf16 (transposed, zero-padded), bb[256] ----------------
__global__ __launch_bounds__(256) void conv_w_kernel(const float* __restrict__ w0,
                                                     const float* __restrict__ b0,
                                                     const float* __restrict__ w1,
                                                     const float* __restrict__ b1,
                                                     short* __restrict__ Wt,
                                                     float* __restrict__ bb) {
    int c = blockIdx.x;          // 0..255 output col
    int k = threadIdx.x;         // 0..255
    const float* w = (c < 128) ? w0 : w1;
    int cc = c & 127;
    if (k < KP) {
        unsigned val = (k < 131) ? f2bf(w[(size_t)k * 128 + cc]) : 0u;
        Wt[(size_t)c * KP + k] = (short)val;
    }
    if (k == 0) bb[c] = (c < 128) ? b0[cc] : b1[cc];
}

// ---------------- fused layer 0+1: normals-gather (L2-resident) + analytic h -> MFMA -> x_1 ----
// h_i = relu(n_i@W0 + b0 + (sum_j n_j)@W1 + deg*b1); then GEMM with layer-1 weights.
__global__ __launch_bounds__(1024, 8) void fused1_kernel(const float4* __restrict__ nrm4, // [N+1]
                                                         const int* __restrict__ cnt,
                                                         const int* __restrict__ adj,
                                                         const float* __restrict__ w0,   // [3][128]
                                                         const float* __restrict__ b0,
                                                         const float* __restrict__ w1,   // [3][128]
                                                         const float* __restrict__ b1,
                                                         const short* __restrict__ Wt,   // [256][184]
                                                         const float* __restrict__ bb,   // [256]
                                                         unsigned* __restrict__ xc_out) {// [N+1][128]
    __shared__ short tileA[16 * KP];     // 5888 B
    __shared__ short tileC[16 * 256];    // 8192 B
    __shared__ float wL[2][3][128];      // layer-0 weights
    __shared__ float bL[2][128];

    int tid  = threadIdx.x;
    int w    = tid >> 6;
    int lane = tid & 63;
    int g    = lane >> 4;
    int ln   = lane & 15;
    int row0 = blockIdx.x * 16;
    int i    = row0 + w;

    // ---- stage layer-0 weights ----
    if (tid < 768) {
        int mm = tid / 384, r = tid - mm * 384;
        (&wL[mm][0][0])[r] = (mm ? w1 : w0)[r];
    } else {
        int t2 = tid - 768;
        if (t2 < 256) bL[t2 >> 7][t2 & 127] = ((t2 >> 7) ? b1 : b0)[t2 & 127];
    }

    // ---- loads: adjacency, self normals; gather neighbor normals (all 64 lanes) ----
    int deg0 = cnt[i];
    int jv = (lane < CAP) ? adj[(size_t)i * CAP + lane] : (int)N_TOT;
    float4 self4 = nrm4[i];
    float4 nj = nrm4[jv];           // sentinel -> zero row (lanes >= deg contribute 0)

    int deg = (deg0 > CAP) ? CAP : deg0;
    deg = __builtin_amdgcn_readfirstlane(deg);
    float degf = (float)deg;

    // ---- wave-sum of neighbor normals ----
    float sx = nj.x, sy = nj.y, sz = nj.z;
    #pragma unroll
    for (int d = 1; d < 64; d <<= 1) {
        sx += __shfl_xor(sx, d);
        sy += __shfl_xor(sy, d);
        sz += __shfl_xor(sz, d);
    }
    __syncthreads();   // weights staged

    // ---- analytic h for this lane's 2 columns ----
    int c0 = 2 * lane, c1 = 2 * lane + 1;
    float h0 = bL[0][c0] + degf * bL[1][c0]
             + self4.x * wL[0][0][c0] + self4.y * wL[0][1][c0] + self4.z * wL[0][2][c0]
             + sx * wL[1][0][c0] + sy * wL[1][1][c0] + sz * wL[1][2][c0];
    float h1 = bL[0][c1] + degf * bL[1][c1]
             + self4.x * wL[0][0][c1] + self4.y * wL[0][1][c1] + self4.z * wL[0][2][c1]
             + sx * wL[1][0][c1] + sy * wL[1][1][c1] + sz * wL[1][2][c1];
    h0 = fmaxf(h0, 0.f);
    h1 = fmaxf(h1, 0.f);

    // ---- tile row: dwords 0..63 = h, 64..79 = normals + pad ----
    unsigned* tA32 = (unsigned*)tileA;
    tA32[w * (KP / 2) + lane] = cvt_pk_bf16(h0, h1);
    if (lane < 16) {
        unsigned v = (lane == 0) ? cvt_pk_bf16(self4.x, self4.y)
                   : (lane == 1) ? cvt_pk_bf16(self4.z, 0.f) : 0u;
        tA32[w * (KP / 2) + 64 + lane] = v;
    }
    __syncthreads();

    // ---- MFMA: wave w computes 16 rows x 16 cols (col block w*16) over K=160 ----
    int cb = w * 16;
    float bv = bb[cb + ln];
    f32x4 acc = {bv, bv, bv, bv};
    #pragma unroll
    for (int kk = 0; kk < KSTEPS; ++kk) {
        bf16x8 bf = *(const bf16x8*)(Wt + (size_t)(cb + ln) * KP + kk * 32 + g * 8);
        bf16x8 af = *(const bf16x8*)(tileA + ln * KP + kk * 32 + g * 8);
        acc = __builtin_amdgcn_mfma_f32_16x16x32_bf16(af, bf, acc, 0, 0, 0);
    }
    #pragma unroll
    for (int j = 0; j < 4; ++j) {
        float po = __shfl_xor(acc[j], 1);
        if (!(ln & 1)) {
            unsigned pk = cvt_pk_bf16(acc[j], po);
            int dd = w * 8 + (ln >> 1);
            int row = g * 4 + j;
            ((unsigned*)tileC)[row * 128 + (dd ^ (g << 3))] = pk;
        }
    }
    __syncthreads();

    int key = (w >> 2) << 3;
    ushort4 v4 = *(const ushort4*)&((unsigned*)tileC)[w * 128 + ((2 * lane) ^ key)];
    ((ushort4*)(xc_out + (size_t)(row0 + w) * 128))[lane] = v4;
}

// ---------------- fused layer 2: 8-deep gather + relu -> LDS tile -> MFMA -> x_2 ----------------
__global__ __launch_bounds__(1024, 8) void fused_kernel(const unsigned* __restrict__ xc_in, // [N+1][128]
                                                        const float4* __restrict__ nrm4,
                                                        const int* __restrict__ cnt,
                                                        const int* __restrict__ adj,
                                                        const short* __restrict__ Wt,      // [256][184]
                                                        const float* __restrict__ bb,      // [256]
                                                        unsigned* __restrict__ xc_out) {   // [N+1][128]
    __shared__ short tileA[16 * KP];
    __shared__ short tileC[16 * 256];
    int tid  = threadIdx.x;
    int w    = tid >> 6;
    int lane = tid & 63;
    int g    = lane >> 4;
    int ln   = lane & 15;
    int row0 = blockIdx.x * 16;
    int i    = row0 + w;

    // ---- early loads ----
    int deg0 = cnt[i];
    int jv = (lane < CAP) ? adj[(size_t)i * CAP + lane] : (int)N_TOT;

    // ---- round 0: 8 unconditional gathers (scalar base via readlane) ----
    const unsigned* x1b = xc_in + 64 + lane;   // + jj*128
    unsigned u[8];
    #pragma unroll
    for (int q = 0; q < 8; ++q) {
        int j = __builtin_amdgcn_readlane(jv, q);
        u[q] = x1b[(size_t)j * 128];
    }
    unsigned selfu = xc_in[(size_t)i * 128 + lane];
    float4 self4 = nrm4[i];
    int cb = w * 16;
    float bv = bb[cb + ln];
    bf16x8 bfrag[KSTEPS];
    #pragma unroll
    for (int kk = 0; kk < KSTEPS; ++kk)
        bfrag[kk] = *(const bf16x8*)(Wt + (size_t)(cb + ln) * KP + kk * 32 + g * 8);

    float a0 = bflo(selfu), a1 = bfhi(selfu);
    float d0 = 0.f, d1 = 0.f;
    #pragma unroll
    for (int q = 0; q < 8; q += 2) {
        a0 += bflo(u[q]);     a1 += bfhi(u[q]);
        d0 += bflo(u[q + 1]); d1 += bfhi(u[q + 1]);
    }
    // ---- extra rounds (deg > 8) ----
    int deg = (deg0 > CAP) ? CAP : deg0;
    deg = __builtin_amdgcn_readfirstlane(deg);
    for (int bq = 8; bq < deg; bq += 8) {
        unsigned v[8];
        #pragma unroll
        for (int q = 0; q < 8; ++q) {
            int j = __builtin_amdgcn_readlane(jv, bq + q);
            v[q] = x1b[(size_t)j * 128];
        }
        #pragma unroll
        for (int q = 0; q < 8; q += 2) {
            a0 += bflo(v[q]);     a1 += bfhi(v[q]);
            d0 += bflo(v[q + 1]); d1 += bfhi(v[q + 1]);
        }
    }
    a0 = fmaxf(a0 + d0, 0.f);
    a1 = fmaxf(a1 + d1, 0.f);

    // ---- tile row ----
    unsigned* tA32 = (unsigned*)tileA;
    tA32[w * (KP / 2) + lane] = cvt_pk_bf16(a0, a1);
    if (lane < 16) {
        unsigned v = (lane == 0) ? cvt_pk_bf16(self4.x, self4.y)
                   : (lane == 1) ? cvt_pk_bf16(self4.z, 0.f) : 0u;
        tA32[w * (KP / 2) + 64 + lane] = v;
    }
    __syncthreads();

    // ---- MFMA ----
    f32x4 acc = {bv, bv, bv, bv};
    #pragma unroll
    for (int kk = 0; kk < KSTEPS; ++kk) {
        bf16x8 af = *(const bf16x8*)(tileA + ln * KP + kk * 32 + g * 8);
        acc = __builtin_amdgcn_mfma_f32_16x16x32_bf16(af, bfrag[kk], acc, 0, 0, 0);
    }
    #pragma unroll
    for (int j = 0; j < 4; ++j) {
        float po = __shfl_xor(acc[j], 1);
        if (!(ln & 1)) {
            unsigned pk = cvt_pk_bf16(acc[j], po);
            int dd = w * 8 + (ln >> 1);
            int row = g * 4 + j;
            ((unsigned*)tileC)[row * 128 + (dd ^ (g << 3))] = pk;
        }
    }
    __syncthreads();

    int key = (w >> 2) << 3;
    ushort4 v4 = *(const ushort4*)&((unsigned*)tileC)[w * 128 + ((2 * lane) ^ key)];
    ((ushort4*)(xc_out + (size_t)(row0 + w) * 128))[lane] = v4;
}

// ---------------- final: 8-deep gather + relu -> h (f32) + deform + vertex update ----------------
__global__ __launch_bounds__(256) void final_fused_kernel(const unsigned* __restrict__ xc_in,
                                                          const int* __restrict__ cnt,
                                                          const int* __restrict__ adj,
                                                          const float* __restrict__ normals,
                                                          const float* __restrict__ verts,
                                                          const float* __restrict__ anchor_v,
                                                          const int* __restrict__ part_id,
                                                          const float* __restrict__ w_off,
                                                          const float* __restrict__ b_off,
                                                          float* __restrict__ hout,
                                                          float* __restrict__ out_verts) {
    __shared__ float wo[131 * 3];
    for (int t = threadIdx.x; t < 131 * 3; t += 256) wo[t] = w_off[t];
    __syncthreads();
    int tid  = threadIdx.x;
    int w    = tid >> 6;
    int lane = tid & 63;
    int i    = blockIdx.x * 4 + w;

    int deg0 = cnt[i];
    int jv = (lane < CAP) ? adj[(size_t)i * CAP + lane] : (int)N_TOT;
    unsigned selfu = xc_in[(size_t)i * 128 + lane];

    const unsigned* x1b = xc_in + 64 + lane;
    unsigned u[8];
    #pragma unroll
    for (int q = 0; q < 8; ++q) {
        int j = __builtin_amdgcn_readlane(jv, q);
        u[q] = x1b[(size_t)j * 128];
    }
    float a0 = bflo(selfu), a1 = bfhi(selfu);
    float d0 = 0.f, d1 = 0.f;
    #pragma unroll
    for (int q = 0; q < 8; q += 2) {
        a0 += bflo(u[q]);     a1 += bfhi(u[q]);
        d0 += bflo(u[q + 1]); d1 += bfhi(u[q + 1]);
    }
    int deg = (deg0 > CAP) ? CAP : deg0;
    deg = __builtin_amdgcn_readfirstlane(deg);
    for (int bq = 8; bq < deg; bq += 8) {
        unsigned v[8];
        #pragma unroll
        for (int q = 0; q < 8; ++q) {
            int j = __builtin_amdgcn_readlane(jv, bq + q);
            v[q] = x1b[(size_t)j * 128];
        }
        #pragma unroll
        for (int q = 0; q < 8; q += 2) {
            a0 += bflo(v[q]);     a1 += bfhi(v[q]);
            d0 += bflo(v[q + 1]); d1 += bfhi(v[q + 1]);
        }
    }
    a0 = fmaxf(a0 + d0, 0.f);
    a1 = fmaxf(a1 + d1, 0.f);

    float2 hv; hv.x = a0; hv.y = a1;
    ((float2*)(hout + (size_t)i * 128))[lane] = hv;

    int cA = 2 * lane, cB = 2 * lane + 1;
    float s0 = a0 * wo[cA * 3 + 0] + a1 * wo[cB * 3 + 0];
    float s1 = a0 * wo[cA * 3 + 1] + a1 * wo[cB * 3 + 1];
    float s2 = a0 * wo[cA * 3 + 2] + a1 * wo[cB * 3 + 2];
    #pragma unroll
    for (int dd = 32; dd; dd >>= 1) {
        s0 += __shfl_xor(s0, dd);
        s1 += __shfl_xor(s1, dd);
        s2 += __shfl_xor(s2, dd);
    }
    if (lane < 3) {
        int v = i % V_MESH;
        float n0 = normals[(size_t)i * 3 + 0];
        float n1 = normals[(size_t)i * 3 + 1];
        float n2 = normals[(size_t)i * 3 + 2];
        float s = (lane == 0) ? s0 : (lane == 1) ? s1 : s2;
        s += n0 * wo[128 * 3 + lane] + n1 * wo[129 * 3 + lane] + n2 * wo[130 * 3 + lane];
        s += b_off[lane];
        float dd2 = tanhf(s);
        float lim = c_LIM[part_id[v]];
        dd2 = fminf(fmaxf(dd2, -lim), lim);
        out_verts[(size_t)i * 3 + lane] =
            verts[(size_t)i * 3 + lane] + dd2 * anchor_v[(size_t)v * 3 + lane];
    }
}

extern "C" void kernel_launch(void* const* d_in, const int* in_sizes, int n_in,
                              void* d_out, int out_size, void* d_ws, size_t ws_size,
                              hipStream_t stream) {
    const float* verts    = (const float*)d_in[0];
    const float* normals  = (const float*)d_in[1];
    const float* anchor_v = (const float*)d_in[2];
    const int*   edges    = (const int*)d_in[3];
    const int*   part_id  = (const int*)d_in[4];
    const float* w0_0 = (const float*)d_in[5];
    const float* b0_0 = (const float*)d_in[6];
    const float* w1_0 = (const float*)d_in[7];
    const float* b1_0 = (const float*)d_in[8];
    const float* w0_1 = (const float*)d_in[9];
    const float* b0_1 = (const float*)d_in[10];
    const float* w1_1 = (const float*)d_in[11];
    const float* b1_1 = (const float*)d_in[12];
    const float* w0_2 = (const float*)d_in[13];
    const float* b0_2 = (const float*)d_in[14];
    const float* w1_2 = (const float*)d_in[15];
    const float* b1_2 = (const float*)d_in[16];
    const float* w_off = (const float*)d_in[17];
    const float* b_off = (const float*)d_in[18];

    float* out_verts = (float*)d_out;
    float* hout = (float*)d_out + (size_t)3 * N_TOT;   // final h (f32)

    // x_1 buffer aliases ALL of d_out (dead until final): [N+1][128] dwords
    unsigned* xcB = (unsigned*)d_out;

    char* p = (char*)d_ws;
    unsigned* xcA = (unsigned*)p;  p += (size_t)(N_TOT + 1) * 128 * 4;   // x_2 buffer
    int*   cnt  = (int*)p;         p += (size_t)N_TOT * 4;
    int*   adj  = (int*)p;         p += (size_t)N_TOT * CAP * 4;
    short* Wt1  = (short*)p;       p += 256 * KP * 2;
    float* bb1  = (float*)p;       p += 256 * 4;
    short* Wt2  = (short*)p;       p += 256 * KP * 2;
    float* bb2  = (float*)p;       p += 256 * 4;
    float4* nrm4 = (float4*)p;     p += (size_t)(N_TOT + 1) * 16;

    hipMemsetAsync(cnt, 0, (size_t)N_TOT * 4, stream);
    hipMemsetAsync(xcA + (size_t)N_TOT * 128, 0, 512, stream);   // zero row A
    hipMemsetAsync(xcB + (size_t)N_TOT * 128, 0, 512, stream);   // zero row B
    fill_adj_kernel<<<(E_TOT + 255) / 256, 256, 0, stream>>>(edges, cnt, adj);
    pad_adj_kernel<<<(N_TOT + 255) / 256, 256, 0, stream>>>(cnt, adj);
    prep_nrm4_kernel<<<(N_TOT + 256) / 256, 256, 0, stream>>>(normals, nrm4);
    conv_w_kernel<<<256, 256, 0, stream>>>(w0_1, b0_1, w1_1, b1_1, Wt1, bb1);
    conv_w_kernel<<<256, 256, 0, stream>>>(w0_2, b0_2, w1_2, b1_2, Wt2, bb2);

    // layers 0+1 fused analytically: normals-gather -> h_0 -> GEMM(W_1) -> x_1 (xcB)
    fused1_kernel<<<N_TOT / 16, 1024, 0, stream>>>(nrm4, cnt, adj, w0_0, b0_0, w1_0, b1_0,
                                                   Wt1, bb1, xcB);
    // layer 2: gather(x_1) -> h_1 -> GEMM(W_2) -> x_2 (xcA)
    fused_kernel<<<N_TOT / 16, 1024, 0, stream>>>(xcB, nrm4, cnt, adj, Wt2, bb2, xcA);
    // final: gather(x_2) -> h_2 + verts (writes overlay dead xcB region)
    final_fused_kernel<<<N_TOT / 4, 256, 0, stream>>>(xcA, cnt, adj, normals, verts,
                                                      anchor_v, part_id, w_off, b_off,
                                                      hout, out_verts);
}

// Round 10
// 471.790 us; speedup vs baseline: 1.0901x; 1.0629x over previous
//
#include <hip/hip_runtime.h>

#define N_TOT 211072   // B*V = 32*6596
#define V_MESH 6596
#define E_TOT 633216   // 3*N
#define CAP 32
#define KP 184         // feats row width in bf16 (368B; MFMA reads cols 0..159)
#define KSTEPS 5       // 5*32 = 160 >= 131

typedef __attribute__((ext_vector_type(8))) short bf16x8;
typedef __attribute__((ext_vector_type(4))) float f32x4;

__constant__ float c_LIM[14] = {0.04f,0.06f,0.04f,0.04f,0.02f,0.02f,0.04f,0.04f,
                                0.03f,0.03f,0.02f,0.02f,0.01f,0.01f};

__device__ __forceinline__ unsigned f2bf(float f) {   // RNE f32->bf16
    unsigned x = __float_as_uint(f);
    return (x + 0x7fffu + ((x >> 16) & 1u)) >> 16;
}
__device__ __forceinline__ float bflo(unsigned u) { return __uint_as_float(u << 16); }
__device__ __forceinline__ float bfhi(unsigned u) { return __uint_as_float(u & 0xffff0000u); }
// HW packed RNE convert: D = {bf16(lo), bf16(hi)}
__device__ __forceinline__ unsigned cvt_pk_bf16(float lo, float hi) {
    unsigned r;
    asm("v_cvt_pk_bf16_f32 %0, %1, %2" : "=v"(r) : "v"(lo), "v"(hi));
    return r;
}

// ---------------- adjacency build ----------------
__global__ __launch_bounds__(256) void fill_adj_kernel(const int* __restrict__ edges,
                                                       int* __restrict__ cnt,
                                                       int* __restrict__ adj) {
    int e = blockIdx.x * 256 + threadIdx.x;
    if (e >= E_TOT) return;
    int2 ed = ((const int2*)edges)[e];
    int p0 = atomicAdd(&cnt[ed.x], 1);
    if (p0 < CAP) adj[(size_t)ed.x * CAP + p0] = ed.y;
    int p1 = atomicAdd(&cnt[ed.y], 1);
    if (p1 < CAP) adj[(size_t)ed.y * CAP + p1] = ed.x;
}

// ---------------- pad adjacency rows with sentinel up to CAP ----------------
__global__ __launch_bounds__(256) void pad_adj_kernel(const int* __restrict__ cnt,
                                                      int* __restrict__ adj) {
    int i = blockIdx.x * 256 + threadIdx.x;
    if (i >= N_TOT) return;
    int deg = cnt[i]; if (deg > CAP) deg = CAP;
    for (int k = deg; k < CAP; ++k) adj[(size_t)i * CAP + k] = N_TOT;
}

// ---------------- normals -> padded float4 rows (zero row at N_TOT) ----------------
__global__ __launch_bounds__(256) void prep_nrm4_kernel(const float* __restrict__ normals,
                                                        float4* __restrict__ nrm4) {
    int i = blockIdx.x * 256 + threadIdx.x;
    if (i > N_TOT) return;
    float4 v = {0.f, 0.f, 0.f, 0.f};
    if (i < N_TOT) {
        v.x = normals[(size_t)i * 3 + 0];
        v.y = normals[(size_t)i * 3 + 1];
        v.z = normals[(size_t)i * 3 + 2];
    }
    nrm4[i] = v;
}

// ---------------- neighbor-normal sums: SS[i] = (sum_j n_j, deg) ----------------
// Gather pool = nrm4 (3.4 MB, L2-resident). Thread per node, 8 loads in flight.
__global__ __launch_bounds__(256) void nsum_kernel(const float4* __restrict__ nrm4,
                                                   const int* __restrict__ cnt,
                                                   const int* __restrict__ adj,
                                                   float4* __restrict__ SS) {
    int i = blockIdx.x * 256 + threadIdx.x;
    if (i >= N_TOT) return;
    int deg = cnt[i]; if (deg > CAP) deg = CAP;
    const int4* a4 = (const int4*)(adj + (size_t)i * CAP);
    int4 A = a4[0], B = a4[1];
    float4 n0 = nrm4[A.x], n1 = nrm4[A.y], n2 = nrm4[A.z], n3 = nrm4[A.w];
    float4 m0 = nrm4[B.x], m1 = nrm4[B.y], m2 = nrm4[B.z], m3 = nrm4[B.w];
    float sx = ((n0.x + n1.x) + (n2.x + n3.x)) + ((m0.x + m1.x) + (m2.x + m3.x));
    float sy = ((n0.y + n1.y) + (n2.y + n3.y)) + ((m0.y + m1.y) + (m2.y + m3.y));
    float sz = ((n0.z + n1.z) + (n2.z + n3.z)) + ((m0.z + m1.z) + (m2.z + m3.z));
    for (int bq = 8; bq < deg; bq += 8) {
        int4 C = a4[bq / 4], D = a4[bq / 4 + 1];
        float4 p0 = nrm4[C.x], p1 = nrm4[C.y], p2 = nrm4[C.z], p3 = nrm4[C.w];
        float4 q0 = nrm4[D.x], q1 = nrm4[D.y], q2 = nrm4[D.z], q3 = nrm4[D.w];
        sx += ((p0.x + p1.x) + (p2.x + p3.x)) + ((q0.x + q1.x) + (q2.x + q3.x));
        sy += ((p0.y + p1.y) + (p2.y + p3.y)) + ((q0.y + q1.y) + (q2.y + q3.y));
        sz += ((p0.z + p1.z) + (p2.z + p3.z)) + ((q0.z + q1.z) + (q2.z + q3.z));
    }
    float4 out; out.x = sx; out.y = sy; out.z = sz; out.w = (float)deg;
    SS[i] = out;
}

// ---------------- weight conversion: Wt[256][184] bf16 (transposed, zero-padded), bb[256] ----------------
__global__ __launch_bounds__(256) void conv_w_kernel(const float* __restrict__ w0,
                                                     const float* __restrict__ b0,
                                                     const float* __restrict__ w1,
                                                     const float* __restrict__ b1,
                                                     short* __restrict__ Wt,
                                                     float* __restrict__ bb) {
    int c = blockIdx.x;          // 0..255 output col
    int k = threadIdx.x;         // 0..255
    const float* w = (c < 128) ? w0 : w1;
    int cc = c & 127;
    if (k < KP) {
        unsigned val = (k < 131) ? f2bf(w[(size_t)k * 128 + cc]) : 0u;
        Wt[(size_t)c * KP + k] = (short)val;
    }
    if (k == 0) bb[c] = (c < 128) ? b0[cc] : b1[cc];
}

// ---------------- fused layer 0+1: analytic h (no gather!) -> MFMA -> x_1 ----------------
// h_i = relu(n_i@W0 + b0 + S_i@W1 + deg_i*b1), S/deg precomputed in SS.
__global__ __launch_bounds__(1024, 8) void fused1_kernel(const float4* __restrict__ nrm4, // [N+1]
                                                         const float4* __restrict__ SS,   // [N]
                                                         const float* __restrict__ w0,    // [3][128]
                                                         const float* __restrict__ b0,
                                                         const float* __restrict__ w1,    // [3][128]
                                                         const float* __restrict__ b1,
                                                         const short* __restrict__ Wt,    // [256][184]
                                                         const float* __restrict__ bb,    // [256]
                                                         unsigned* __restrict__ xc_out) { // [N+1][128]
    __shared__ short tileA[16 * KP];     // 5888 B
    __shared__ short tileC[16 * 256];    // 8192 B
    __shared__ float wL[2][3][128];      // layer-0 weights
    __shared__ float bL[2][128];

    int tid  = threadIdx.x;
    int w    = tid >> 6;
    int lane = tid & 63;
    int g    = lane >> 4;
    int ln   = lane & 15;
    int row0 = blockIdx.x * 16;
    int i    = row0 + w;

    // ---- stage layer-0 weights ----
    if (tid < 768) {
        int mm = tid / 384, r = tid - mm * 384;
        (&wL[mm][0][0])[r] = (mm ? w1 : w0)[r];
    } else {
        int t2 = tid - 768;
        if (t2 < 256) bL[t2 >> 7][t2 & 127] = ((t2 >> 7) ? b1 : b0)[t2 & 127];
    }

    // ---- per-node inputs (uniform per wave, streaming) ----
    float4 self4 = nrm4[i];
    float4 S4 = SS[i];
    float degf = S4.w;
    __syncthreads();   // weights staged

    // ---- analytic h for this lane's 2 columns ----
    int c0 = 2 * lane, c1 = 2 * lane + 1;
    float h0 = bL[0][c0] + degf * bL[1][c0]
             + self4.x * wL[0][0][c0] + self4.y * wL[0][1][c0] + self4.z * wL[0][2][c0]
             + S4.x * wL[1][0][c0] + S4.y * wL[1][1][c0] + S4.z * wL[1][2][c0];
    float h1 = bL[0][c1] + degf * bL[1][c1]
             + self4.x * wL[0][0][c1] + self4.y * wL[0][1][c1] + self4.z * wL[0][2][c1]
             + S4.x * wL[1][0][c1] + S4.y * wL[1][1][c1] + S4.z * wL[1][2][c1];
    h0 = fmaxf(h0, 0.f);
    h1 = fmaxf(h1, 0.f);

    // ---- tile row: dwords 0..63 = h, 64..79 = normals + pad ----
    unsigned* tA32 = (unsigned*)tileA;
    tA32[w * (KP / 2) + lane] = cvt_pk_bf16(h0, h1);
    if (lane < 16) {
        unsigned v = (lane == 0) ? cvt_pk_bf16(self4.x, self4.y)
                   : (lane == 1) ? cvt_pk_bf16(self4.z, 0.f) : 0u;
        tA32[w * (KP / 2) + 64 + lane] = v;
    }
    __syncthreads();

    // ---- MFMA: wave w computes 16 rows x 16 cols (col block w*16) over K=160 ----
    int cb = w * 16;
    float bv = bb[cb + ln];
    f32x4 acc = {bv, bv, bv, bv};
    #pragma unroll
    for (int kk = 0; kk < KSTEPS; ++kk) {
        bf16x8 bf = *(const bf16x8*)(Wt + (size_t)(cb + ln) * KP + kk * 32 + g * 8);
        bf16x8 af = *(const bf16x8*)(tileA + ln * KP + kk * 32 + g * 8);
        acc = __builtin_amdgcn_mfma_f32_16x16x32_bf16(af, bf, acc, 0, 0, 0);
    }
    #pragma unroll
    for (int j = 0; j < 4; ++j) {
        float po = __shfl_xor(acc[j], 1);
        if (!(ln & 1)) {
            unsigned pk = cvt_pk_bf16(acc[j], po);
            int dd = w * 8 + (ln >> 1);
            int row = g * 4 + j;
            ((unsigned*)tileC)[row * 128 + (dd ^ (g << 3))] = pk;
        }
    }
    __syncthreads();

    int key = (w >> 2) << 3;
    ushort4 v4 = *(const ushort4*)&((unsigned*)tileC)[w * 128 + ((2 * lane) ^ key)];
    ((ushort4*)(xc_out + (size_t)(row0 + w) * 128))[lane] = v4;
}

// ---------------- fused layer 2: 8-deep gather + relu -> LDS tile -> MFMA -> x_2 ----------------
__global__ __launch_bounds__(1024, 8) void fused_kernel(const unsigned* __restrict__ xc_in, // [N+1][128]
                                                        const float4* __restrict__ nrm4,
                                                        const int* __restrict__ cnt,
                                                        const int* __restrict__ adj,
                                                        const short* __restrict__ Wt,      // [256][184]
                                                        const float* __restrict__ bb,      // [256]
                                                        unsigned* __restrict__ xc_out) {   // [N+1][128]
    __shared__ short tileA[16 * KP];
    __shared__ short tileC[16 * 256];
    int tid  = threadIdx.x;
    int w    = tid >> 6;
    int lane = tid & 63;
    int g    = lane >> 4;
    int ln   = lane & 15;
    int row0 = blockIdx.x * 16;
    int i    = row0 + w;

    // ---- early loads ----
    int deg0 = cnt[i];
    int jv = (lane < CAP) ? adj[(size_t)i * CAP + lane] : (int)N_TOT;

    // ---- round 0: 8 unconditional gathers (scalar base via readlane) ----
    const unsigned* x1b = xc_in + 64 + lane;   // + jj*128
    unsigned u[8];
    #pragma unroll
    for (int q = 0; q < 8; ++q) {
        int j = __builtin_amdgcn_readlane(jv, q);
        u[q] = x1b[(size_t)j * 128];
    }
    unsigned selfu = xc_in[(size_t)i * 128 + lane];
    float4 self4 = nrm4[i];
    int cb = w * 16;
    float bv = bb[cb + ln];
    bf16x8 bfrag[KSTEPS];
    #pragma unroll
    for (int kk = 0; kk < KSTEPS; ++kk)
        bfrag[kk] = *(const bf16x8*)(Wt + (size_t)(cb + ln) * KP + kk * 32 + g * 8);

    float a0 = bflo(selfu), a1 = bfhi(selfu);
    float d0 = 0.f, d1 = 0.f;
    #pragma unroll
    for (int q = 0; q < 8; q += 2) {
        a0 += bflo(u[q]);     a1 += bfhi(u[q]);
        d0 += bflo(u[q + 1]); d1 += bfhi(u[q + 1]);
    }
    // ---- extra rounds (deg > 8) ----
    int deg = (deg0 > CAP) ? CAP : deg0;
    deg = __builtin_amdgcn_readfirstlane(deg);
    for (int bq = 8; bq < deg; bq += 8) {
        unsigned v[8];
        #pragma unroll
        for (int q = 0; q < 8; ++q) {
            int j = __builtin_amdgcn_readlane(jv, bq + q);
            v[q] = x1b[(size_t)j * 128];
        }
        #pragma unroll
        for (int q = 0; q < 8; q += 2) {
            a0 += bflo(v[q]);     a1 += bfhi(v[q]);
            d0 += bflo(v[q + 1]); d1 += bfhi(v[q + 1]);
        }
    }
    a0 = fmaxf(a0 + d0, 0.f);
    a1 = fmaxf(a1 + d1, 0.f);

    // ---- tile row ----
    unsigned* tA32 = (unsigned*)tileA;
    tA32[w * (KP / 2) + lane] = cvt_pk_bf16(a0, a1);
    if (lane < 16) {
        unsigned v = (lane == 0) ? cvt_pk_bf16(self4.x, self4.y)
                   : (lane == 1) ? cvt_pk_bf16(self4.z, 0.f) : 0u;
        tA32[w * (KP / 2) + 64 + lane] = v;
    }
    __syncthreads();

    // ---- MFMA ----
    f32x4 acc = {bv, bv, bv, bv};
    #pragma unroll
    for (int kk = 0; kk < KSTEPS; ++kk) {
        bf16x8 af = *(const bf16x8*)(tileA + ln * KP + kk * 32 + g * 8);
        acc = __builtin_amdgcn_mfma_f32_16x16x32_bf16(af, bfrag[kk], acc, 0, 0, 0);
    }
    #pragma unroll
    for (int j = 0; j < 4; ++j) {
        float po = __shfl_xor(acc[j], 1);
        if (!(ln & 1)) {
            unsigned pk = cvt_pk_bf16(acc[j], po);
            int dd = w * 8 + (ln >> 1);
            int row = g * 4 + j;
            ((unsigned*)tileC)[row * 128 + (dd ^ (g << 3))] = pk;
        }
    }
    __syncthreads();

    int key = (w >> 2) << 3;
    ushort4 v4 = *(const ushort4*)&((unsigned*)tileC)[w * 128 + ((2 * lane) ^ key)];
    ((ushort4*)(xc_out + (size_t)(row0 + w) * 128))[lane] = v4;
}

// ---------------- final: 8-deep gather + relu -> h (f32) + deform + vertex update ----------------
__global__ __launch_bounds__(256) void final_fused_kernel(const unsigned* __restrict__ xc_in,
                                                          const int* __restrict__ cnt,
                                                          const int* __restrict__ adj,
                                                          const float* __restrict__ normals,
                                                          const float* __restrict__ verts,
                                                          const float* __restrict__ anchor_v,
                                                          const int* __restrict__ part_id,
                                                          const float* __restrict__ w_off,
                                                          const float* __restrict__ b_off,
                                                          float* __restrict__ hout,
                                                          float* __restrict__ out_verts) {
    __shared__ float wo[131 * 3];
    for (int t = threadIdx.x; t < 131 * 3; t += 256) wo[t] = w_off[t];
    __syncthreads();
    int tid  = threadIdx.x;
    int w    = tid >> 6;
    int lane = tid & 63;
    int i    = blockIdx.x * 4 + w;

    int deg0 = cnt[i];
    int jv = (lane < CAP) ? adj[(size_t)i * CAP + lane] : (int)N_TOT;
    unsigned selfu = xc_in[(size_t)i * 128 + lane];

    const unsigned* x1b = xc_in + 64 + lane;
    unsigned u[8];
    #pragma unroll
    for (int q = 0; q < 8; ++q) {
        int j = __builtin_amdgcn_readlane(jv, q);
        u[q] = x1b[(size_t)j * 128];
    }
    float a0 = bflo(selfu), a1 = bfhi(selfu);
    float d0 = 0.f, d1 = 0.f;
    #pragma unroll
    for (int q = 0; q < 8; q += 2) {
        a0 += bflo(u[q]);     a1 += bfhi(u[q]);
        d0 += bflo(u[q + 1]); d1 += bfhi(u[q + 1]);
    }
    int deg = (deg0 > CAP) ? CAP : deg0;
    deg = __builtin_amdgcn_readfirstlane(deg);
    for (int bq = 8; bq < deg; bq += 8) {
        unsigned v[8];
        #pragma unroll
        for (int q = 0; q < 8; ++q) {
            int j = __builtin_amdgcn_readlane(jv, bq + q);
            v[q] = x1b[(size_t)j * 128];
        }
        #pragma unroll
        for (int q = 0; q < 8; q += 2) {
            a0 += bflo(v[q]);     a1 += bfhi(v[q]);
            d0 += bflo(v[q + 1]); d1 += bfhi(v[q + 1]);
        }
    }
    a0 = fmaxf(a0 + d0, 0.f);
    a1 = fmaxf(a1 + d1, 0.f);

    float2 hv; hv.x = a0; hv.y = a1;
    ((float2*)(hout + (size_t)i * 128))[lane] = hv;

    int cA = 2 * lane, cB = 2 * lane + 1;
    float s0 = a0 * wo[cA * 3 + 0] + a1 * wo[cB * 3 + 0];
    float s1 = a0 * wo[cA * 3 + 1] + a1 * wo[cB * 3 + 1];
    float s2 = a0 * wo[cA * 3 + 2] + a1 * wo[cB * 3 + 2];
    #pragma unroll
    for (int dd = 32; dd; dd >>= 1) {
        s0 += __shfl_xor(s0, dd);
        s1 += __shfl_xor(s1, dd);
        s2 += __shfl_xor(s2, dd);
    }
    if (lane < 3) {
        int v = i % V_MESH;
        float n0 = normals[(size_t)i * 3 + 0];
        float n1 = normals[(size_t)i * 3 + 1];
        float n2 = normals[(size_t)i * 3 + 2];
        float s = (lane == 0) ? s0 : (lane == 1) ? s1 : s2;
        s += n0 * wo[128 * 3 + lane] + n1 * wo[129 * 3 + lane] + n2 * wo[130 * 3 + lane];
        s += b_off[lane];
        float dd2 = tanhf(s);
        float lim = c_LIM[part_id[v]];
        dd2 = fminf(fmaxf(dd2, -lim), lim);
        out_verts[(size_t)i * 3 + lane] =
            verts[(size_t)i * 3 + lane] + dd2 * anchor_v[(size_t)v * 3 + lane];
    }
}

extern "C" void kernel_launch(void* const* d_in, const int* in_sizes, int n_in,
                              void* d_out, int out_size, void* d_ws, size_t ws_size,
                              hipStream_t stream) {
    const float* verts    = (const float*)d_in[0];
    const float* normals  = (const float*)d_in[1];
    const float* anchor_v = (const float*)d_in[2];
    const int*   edges    = (const int*)d_in[3];
    const int*   part_id  = (const int*)d_in[4];
    const float* w0_0 = (const float*)d_in[5];
    const float* b0_0 = (const float*)d_in[6];
    const float* w1_0 = (const float*)d_in[7];
    const float* b1_0 = (const float*)d_in[8];
    const float* w0_1 = (const float*)d_in[9];
    const float* b0_1 = (const float*)d_in[10];
    const float* w1_1 = (const float*)d_in[11];
    const float* b1_1 = (const float*)d_in[12];
    const float* w0_2 = (const float*)d_in[13];
    const float* b0_2 = (const float*)d_in[14];
    const float* w1_2 = (const float*)d_in[15];
    const float* b1_2 = (const float*)d_in[16];
    const float* w_off = (const float*)d_in[17];
    const float* b_off = (const float*)d_in[18];

    float* out_verts = (float*)d_out;
    float* hout = (float*)d_out + (size_t)3 * N_TOT;   // final h (f32)

    // x_1 buffer aliases ALL of d_out (dead until final): [N+1][128] dwords
    unsigned* xcB = (unsigned*)d_out;

    char* p = (char*)d_ws;
    unsigned* xcA = (unsigned*)p;  p += (size_t)(N_TOT + 1) * 128 * 4;   // x_2 buffer
    int*   cnt  = (int*)p;         p += (size_t)N_TOT * 4;
    int*   adj  = (int*)p;         p += (size_t)N_TOT * CAP * 4;
    short* Wt1  = (short*)p;       p += 256 * KP * 2;
    float* bb1  = (float*)p;       p += 256 * 4;
    short* Wt2  = (short*)p;       p += 256 * KP * 2;
    float* bb2  = (float*)p;       p += 256 * 4;
    float4* nrm4 = (float4*)p;     p += (size_t)(N_TOT + 1) * 16;
    float4* SS   = (float4*)p;     p += (size_t)N_TOT * 16;

    hipMemsetAsync(cnt, 0, (size_t)N_TOT * 4, stream);
    hipMemsetAsync(xcA + (size_t)N_TOT * 128, 0, 512, stream);   // zero row A
    hipMemsetAsync(xcB + (size_t)N_TOT * 128, 0, 512, stream);   // zero row B
    fill_adj_kernel<<<(E_TOT + 255) / 256, 256, 0, stream>>>(edges, cnt, adj);
    pad_adj_kernel<<<(N_TOT + 255) / 256, 256, 0, stream>>>(cnt, adj);
    prep_nrm4_kernel<<<(N_TOT + 256) / 256, 256, 0, stream>>>(normals, nrm4);
    conv_w_kernel<<<256, 256, 0, stream>>>(w0_1, b0_1, w1_1, b1_1, Wt1, bb1);
    conv_w_kernel<<<256, 256, 0, stream>>>(w0_2, b0_2, w1_2, b1_2, Wt2, bb2);
    nsum_kernel<<<(N_TOT + 255) / 256, 256, 0, stream>>>(nrm4, cnt, adj, SS);

    // layers 0+1: analytic h (no gather) -> GEMM(W_1) -> x_1 (xcB)
    fused1_kernel<<<N_TOT / 16, 1024, 0, stream>>>(nrm4, SS, w0_0, b0_0, w1_0, b1_0,
                                                   Wt1, bb1, xcB);
    // layer 2: gather(x_1) -> h_1 -> GEMM(W_2) -> x_2 (xcA)
    fused_kernel<<<N_TOT / 16, 1024, 0, stream>>>(xcB, nrm4, cnt, adj, Wt2, bb2, xcA);
    // final: gather(x_2) -> h_2 + verts (writes overlay dead xcB region)
    final_fused_kernel<<<N_TOT / 4, 256, 0, stream>>>(xcA, cnt, adj, normals, verts,
                                                      anchor_v, part_id, w_off, b_off,
                                                      hout, out_verts);
}

// Round 11
// 409.382 us; speedup vs baseline: 1.2562x; 1.1524x over previous
//
#include <hip/hip_runtime.h>

#define N_TOT 211072   // B*V = 32*6596
#define V_MESH 6596
#define E_TOT 633216   // 3*N
#define CAP 32
#define KD 264         // tileA/Wt row stride in bf16 (132 dwords, mod32=4 -> 2-way banks)
#define KSTEPS 8       // K = 256 = [h(128) | S(128)]

typedef __attribute__((ext_vector_type(8))) short bf16x8;
typedef __attribute__((ext_vector_type(4))) float f32x4;

__constant__ float c_LIM[14] = {0.04f,0.06f,0.04f,0.04f,0.02f,0.02f,0.04f,0.04f,
                                0.03f,0.03f,0.02f,0.02f,0.01f,0.01f};

__device__ __forceinline__ unsigned f2bf(float f) {   // RNE f32->bf16
    unsigned x = __float_as_uint(f);
    return (x + 0x7fffu + ((x >> 16) & 1u)) >> 16;
}
__device__ __forceinline__ float bflo(unsigned u) { return __uint_as_float(u << 16); }
__device__ __forceinline__ float bfhi(unsigned u) { return __uint_as_float(u & 0xffff0000u); }
__device__ __forceinline__ unsigned cvt_pk_bf16(float lo, float hi) {
    unsigned r;
    asm("v_cvt_pk_bf16_f32 %0, %1, %2" : "=v"(r) : "v"(lo), "v"(hi));
    return r;
}

// ---------------- adjacency build ----------------
__global__ __launch_bounds__(256) void fill_adj_kernel(const int* __restrict__ edges,
                                                       int* __restrict__ cnt,
                                                       int* __restrict__ adj) {
    int e = blockIdx.x * 256 + threadIdx.x;
    if (e >= E_TOT) return;
    int2 ed = ((const int2*)edges)[e];
    int p0 = atomicAdd(&cnt[ed.x], 1);
    if (p0 < CAP) adj[(size_t)ed.x * CAP + p0] = ed.y;
    int p1 = atomicAdd(&cnt[ed.y], 1);
    if (p1 < CAP) adj[(size_t)ed.y * CAP + p1] = ed.x;
}

// ---------------- pad adjacency rows with sentinel up to CAP ----------------
__global__ __launch_bounds__(256) void pad_adj_kernel(const int* __restrict__ cnt,
                                                      int* __restrict__ adj) {
    int i = blockIdx.x * 256 + threadIdx.x;
    if (i >= N_TOT) return;
    int deg = cnt[i]; if (deg > CAP) deg = CAP;
    for (int k = deg; k < CAP; ++k) adj[(size_t)i * CAP + k] = N_TOT;
}

// ---------------- normals -> padded float4 rows (zero row at N_TOT) ----------------
__global__ __launch_bounds__(256) void prep_nrm4_kernel(const float* __restrict__ normals,
                                                        float4* __restrict__ nrm4) {
    int i = blockIdx.x * 256 + threadIdx.x;
    if (i > N_TOT) return;
    float4 v = {0.f, 0.f, 0.f, 0.f};
    if (i < N_TOT) {
        v.x = normals[(size_t)i * 3 + 0];
        v.y = normals[(size_t)i * 3 + 1];
        v.z = normals[(size_t)i * 3 + 2];
    }
    nrm4[i] = v;
}

// ---------------- neighbor-normal sums: SS[i] = (sum_j n_j, deg) ----------------
__global__ __launch_bounds__(256) void nsum_kernel(const float4* __restrict__ nrm4,
                                                   const int* __restrict__ cnt,
                                                   const int* __restrict__ adj,
                                                   float4* __restrict__ SS) {
    int i = blockIdx.x * 256 + threadIdx.x;
    if (i >= N_TOT) return;
    int deg = cnt[i]; if (deg > CAP) deg = CAP;
    const int4* a4 = (const int4*)(adj + (size_t)i * CAP);
    int4 A = a4[0], B = a4[1];
    float4 n0 = nrm4[A.x], n1 = nrm4[A.y], n2 = nrm4[A.z], n3 = nrm4[A.w];
    float4 m0 = nrm4[B.x], m1 = nrm4[B.y], m2 = nrm4[B.z], m3 = nrm4[B.w];
    float sx = ((n0.x + n1.x) + (n2.x + n3.x)) + ((m0.x + m1.x) + (m2.x + m3.x));
    float sy = ((n0.y + n1.y) + (n2.y + n3.y)) + ((m0.y + m1.y) + (m2.y + m3.y));
    float sz = ((n0.z + n1.z) + (n2.z + n3.z)) + ((m0.z + m1.z) + (m2.z + m3.z));
    for (int bq = 8; bq < deg; bq += 8) {
        int4 C = a4[bq / 4], D = a4[bq / 4 + 1];
        float4 p0 = nrm4[C.x], p1 = nrm4[C.y], p2 = nrm4[C.z], p3 = nrm4[C.w];
        float4 q0 = nrm4[D.x], q1 = nrm4[D.y], q2 = nrm4[D.z], q3 = nrm4[D.w];
        sx += ((p0.x + p1.x) + (p2.x + p3.x)) + ((q0.x + q1.x) + (q2.x + q3.x));
        sy += ((p0.y + p1.y) + (p2.y + p3.y)) + ((q0.y + q1.y) + (q2.y + q3.y));
        sz += ((p0.z + p1.z) + (p2.z + p3.z)) + ((q0.z + q1.z) + (q2.z + q3.z));
    }
    float4 out; out.x = sx; out.y = sy; out.z = sz; out.w = (float)deg;
    SS[i] = out;
}

// ---------------- weight conversion for fused layers ----------------
// Wt[128 cols][KD]: k<128 -> w0[k][c] (h part), 128<=k<256 -> w1[k-128][c] (S part), pad 0.
// hdA[c]={b0,b1,w0n0,w0n1}, hdB[c]={w0n2,w1n0,w1n1,w1n2}  (n/Sn/deg bias head)
__global__ __launch_bounds__(256) void conv_w2_kernel(const float* __restrict__ w0,
                                                      const float* __restrict__ b0,
                                                      const float* __restrict__ w1,
                                                      const float* __restrict__ b1,
                                                      short* __restrict__ Wt,
                                                      float4* __restrict__ hdA,
                                                      float4* __restrict__ hdB) {
    int c = blockIdx.x;   // 0..127
    for (int k = threadIdx.x; k < KD; k += 256) {
        unsigned val = 0u;
        if (k < 128)      val = f2bf(w0[(size_t)k * 128 + c]);
        else if (k < 256) val = f2bf(w1[(size_t)(k - 128) * 128 + c]);
        Wt[(size_t)c * KD + k] = (short)val;
    }
    if (threadIdx.x == 0) {
        hdA[c] = make_float4(b0[c], b1[c], w0[128 * 128 + c], w0[129 * 128 + c]);
        hdB[c] = make_float4(w0[130 * 128 + c], w1[128 * 128 + c],
                             w1[129 * 128 + c], w1[130 * 128 + c]);
    }
}

// ---------------- layer 0: analytic h_1 (no gather, no GEMM) ----------------
__global__ __launch_bounds__(1024) void fused1_kernel(const float4* __restrict__ nrm4,
                                                      const float4* __restrict__ SS,
                                                      const float* __restrict__ w0,
                                                      const float* __restrict__ b0,
                                                      const float* __restrict__ w1,
                                                      const float* __restrict__ b1,
                                                      unsigned* __restrict__ hout) { // [N+1][64]
    __shared__ float wL[2][3][128];
    __shared__ float bL[2][128];
    int tid  = threadIdx.x;
    int w    = tid >> 6;
    int lane = tid & 63;
    int i    = blockIdx.x * 16 + w;

    if (tid < 768) {
        int mm = tid / 384, r = tid - mm * 384;
        (&wL[mm][0][0])[r] = (mm ? w1 : w0)[r];
    } else if (tid < 1024) {
        int t2 = tid - 768;
        if (t2 < 256) bL[t2 >> 7][t2 & 127] = ((t2 >> 7) ? b1 : b0)[t2 & 127];
    }
    float4 self4 = nrm4[i];
    float4 S4 = SS[i];
    float degf = S4.w;
    __syncthreads();

    int c0 = 2 * lane, c1 = 2 * lane + 1;
    float h0 = bL[0][c0] + degf * bL[1][c0]
             + self4.x * wL[0][0][c0] + self4.y * wL[0][1][c0] + self4.z * wL[0][2][c0]
             + S4.x * wL[1][0][c0] + S4.y * wL[1][1][c0] + S4.z * wL[1][2][c0];
    float h1 = bL[0][c1] + degf * bL[1][c1]
             + self4.x * wL[0][0][c1] + self4.y * wL[0][1][c1] + self4.z * wL[0][2][c1]
             + S4.x * wL[1][0][c1] + S4.y * wL[1][1][c1] + S4.z * wL[1][2][c1];
    hout[(size_t)i * 64 + lane] = cvt_pk_bf16(fmaxf(h0, 0.f), fmaxf(h1, 0.f));
}

// ---------------- fused layer (1,2): gather Sum(h) -> [h|S] GEMM + bias head -> h' ----------------
// 512 threads = 8 waves, 16 rows/block; wave w owns nodes 2w, 2w+1 (16 gathers in flight).
template<int LAST>
__global__ __launch_bounds__(512, 4) void fused2_kernel(const unsigned* __restrict__ hin, // [N+1][64]
                                                        const float4* __restrict__ nrm4,
                                                        const float4* __restrict__ SS,
                                                        const int* __restrict__ cnt,
                                                        const int* __restrict__ adj,
                                                        const short* __restrict__ Wt,    // [128][KD]
                                                        const float4* __restrict__ hdA,
                                                        const float4* __restrict__ hdB,
                                                        unsigned* __restrict__ hnext,    // !LAST
                                                        const float* __restrict__ verts, // LAST...
                                                        const float* __restrict__ anchor_v,
                                                        const int* __restrict__ part_id,
                                                        const float* __restrict__ w_off,
                                                        const float* __restrict__ b_off,
                                                        float* __restrict__ houtf,
                                                        float* __restrict__ out_verts) {
    __shared__ short tileA[16 * KD];       // 8448 B: [h | S | pad]
    __shared__ unsigned tileC[16 * 64];    // 4096 B (non-LAST staging)
    __shared__ float headL[16][8];         // n.xyz, deg, Sn.xyz
    __shared__ float woL[131 * 3];         // LAST
    __shared__ float partL[8][16][3];      // LAST

    int tid  = threadIdx.x;
    int w    = tid >> 6;
    int lane = tid & 63;
    int g    = lane >> 4;
    int ln   = lane & 15;
    int row0 = blockIdx.x * 16;
    int rA   = 2 * w, rB = 2 * w + 1;
    int iA   = row0 + rA, iB = row0 + rB;

    if (LAST) {
        for (int t = tid; t < 131 * 3; t += 512) woL[t] = w_off[t];
    }

    // ---- adjacency (A in lanes 0..31, B in lanes 32..63) + self + head data ----
    int node = (lane < 32) ? iA : iB;
    int jv = adj[(size_t)node * CAP + (lane & 31)];
    int degA = cnt[iA]; degA = (degA > CAP) ? CAP : degA;
    int degB = cnt[iB]; degB = (degB > CAP) ? CAP : degB;
    unsigned selfA = hin[(size_t)iA * 64 + lane];
    unsigned selfB = hin[(size_t)iB * 64 + lane];
    float4 nn = nrm4[node];
    float4 sv = SS[node];
    if ((lane & 31) == 0) {
        int r = rA + (lane >> 5);
        headL[r][0] = nn.x; headL[r][1] = nn.y; headL[r][2] = nn.z; headL[r][3] = sv.w;
        headL[r][4] = sv.x; headL[r][5] = sv.y; headL[r][6] = sv.z; headL[r][7] = 0.f;
    }

    // ---- gather round 0: 8+8 unconditional loads in flight ----
    const unsigned* hb = hin + lane;
    unsigned uA[8], uB[8];
    #pragma unroll
    for (int q = 0; q < 8; ++q) {
        int jA = __builtin_amdgcn_readlane(jv, q);
        int jB = __builtin_amdgcn_readlane(jv, 32 + q);
        uA[q] = hb[(size_t)jA * 64];
        uB[q] = hb[(size_t)jB * 64];
    }
    float sA0 = 0.f, sA1 = 0.f, sB0 = 0.f, sB1 = 0.f;
    #pragma unroll
    for (int q = 0; q < 8; ++q) {
        sA0 += bflo(uA[q]); sA1 += bfhi(uA[q]);
        sB0 += bflo(uB[q]); sB1 += bfhi(uB[q]);
    }
    degA = __builtin_amdgcn_readfirstlane(degA);
    degB = __builtin_amdgcn_readfirstlane(degB);
    for (int bq = 8; bq < degA; bq += 8) {
        unsigned v[8];
        #pragma unroll
        for (int q = 0; q < 8; ++q) {
            int j = __builtin_amdgcn_readlane(jv, bq + q);
            v[q] = hb[(size_t)j * 64];
        }
        #pragma unroll
        for (int q = 0; q < 8; ++q) { sA0 += bflo(v[q]); sA1 += bfhi(v[q]); }
    }
    for (int bq = 8; bq < degB; bq += 8) {
        unsigned v[8];
        #pragma unroll
        for (int q = 0; q < 8; ++q) {
            int j = __builtin_amdgcn_readlane(jv, 32 + bq + q);
            v[q] = hb[(size_t)j * 64];
        }
        #pragma unroll
        for (int q = 0; q < 8; ++q) { sB0 += bflo(v[q]); sB1 += bfhi(v[q]); }
    }

    // ---- tileA rows: [self h (64 dw) | S (64 dw) | pad (4 dw)] ----
    unsigned* tA = (unsigned*)tileA;
    tA[rA * 132 + lane]      = selfA;
    tA[rB * 132 + lane]      = selfB;
    tA[rA * 132 + 64 + lane] = cvt_pk_bf16(sA0, sA1);
    tA[rB * 132 + 64 + lane] = cvt_pk_bf16(sB0, sB1);
    if (lane < 4) {
        tA[rA * 132 + 128 + lane] = 0u;
        tA[rB * 132 + 128 + lane] = 0u;
    }
    __syncthreads();

    // ---- MFMA: wave w -> col block w*16, 16 rows, K=256 ----
    int cb = w * 16, c = cb + ln;
    float4 hA = hdA[c], hB = hdB[c];
    bf16x8 bfrag[KSTEPS];
    #pragma unroll
    for (int kk = 0; kk < KSTEPS; ++kk)
        bfrag[kk] = *(const bf16x8*)(Wt + (size_t)c * KD + kk * 32 + g * 8);

    f32x4 acc;
    #pragma unroll
    for (int j = 0; j < 4; ++j) {
        int r = g * 4 + j;
        acc[j] = hA.x + headL[r][3] * hA.y
               + headL[r][0] * hA.z + headL[r][1] * hA.w + headL[r][2] * hB.x
               + headL[r][4] * hB.y + headL[r][5] * hB.z + headL[r][6] * hB.w;
    }
    #pragma unroll
    for (int kk = 0; kk < KSTEPS; ++kk) {
        bf16x8 af = *(const bf16x8*)(tileA + ln * KD + kk * 32 + g * 8);
        acc = __builtin_amdgcn_mfma_f32_16x16x32_bf16(af, bfrag[kk], acc, 0, 0, 0);
    }
    #pragma unroll
    for (int j = 0; j < 4; ++j) acc[j] = fmaxf(acc[j], 0.f);

    if (!LAST) {
        // pack pairs, swizzled store, coalesced row writeback
        #pragma unroll
        for (int j = 0; j < 4; ++j) {
            float po = __shfl_xor(acc[j], 1);
            if (!(ln & 1)) {
                unsigned pk = cvt_pk_bf16(acc[j], po);
                int r = g * 4 + j;
                int d = (cb + ln) >> 1;
                tileC[r * 64 + (d ^ ((r & 3) << 3))] = pk;
            }
        }
        __syncthreads();
        int r2 = 2 * w + (lane >> 5);
        int d2 = (lane & 31) * 2;
        int key = (r2 & 3) << 3;
        uint2 v2 = *(const uint2*)&tileC[r2 * 64 + (d2 ^ key)];
        *(uint2*)(hnext + (size_t)(row0 + r2) * 64 + d2) = v2;
    } else {
        // h (f32) direct write: 4 x 64B segments per store
        #pragma unroll
        for (int j = 0; j < 4; ++j) {
            int r = g * 4 + j;
            houtf[(size_t)(row0 + r) * 128 + c] = acc[j];
        }
        // offset head partials: reduce over 16-lane col groups
        #pragma unroll
        for (int j = 0; j < 4; ++j) {
            int r = g * 4 + j;
            float p0 = acc[j] * woL[c * 3 + 0];
            float p1 = acc[j] * woL[c * 3 + 1];
            float p2 = acc[j] * woL[c * 3 + 2];
            #pragma unroll
            for (int d = 1; d < 16; d <<= 1) {
                p0 += __shfl_xor(p0, d);
                p1 += __shfl_xor(p1, d);
                p2 += __shfl_xor(p2, d);
            }
            if (ln == 0) {
                partL[w][r][0] = p0; partL[w][r][1] = p1; partL[w][r][2] = p2;
            }
        }
        __syncthreads();
        if (tid < 48) {
            int r = tid / 3, t = tid - r * 3;
            int i = row0 + r;
            float s = 0.f;
            #pragma unroll
            for (int ww = 0; ww < 8; ++ww) s += partL[ww][r][t];
            s += headL[r][0] * woL[128 * 3 + t] + headL[r][1] * woL[129 * 3 + t]
               + headL[r][2] * woL[130 * 3 + t] + b_off[t];
            float dd = tanhf(s);
            int v = i % V_MESH;
            float lim = c_LIM[part_id[v]];
            dd = fminf(fmaxf(dd, -lim), lim);
            out_verts[(size_t)i * 3 + t] =
                verts[(size_t)i * 3 + t] + dd * anchor_v[(size_t)v * 3 + t];
        }
    }
}

extern "C" void kernel_launch(void* const* d_in, const int* in_sizes, int n_in,
                              void* d_out, int out_size, void* d_ws, size_t ws_size,
                              hipStream_t stream) {
    const float* verts    = (const float*)d_in[0];
    const float* normals  = (const float*)d_in[1];
    const float* anchor_v = (const float*)d_in[2];
    const int*   edges    = (const int*)d_in[3];
    const int*   part_id  = (const int*)d_in[4];
    const float* w0_0 = (const float*)d_in[5];
    const float* b0_0 = (const float*)d_in[6];
    const float* w1_0 = (const float*)d_in[7];
    const float* b1_0 = (const float*)d_in[8];
    const float* w0_1 = (const float*)d_in[9];
    const float* b0_1 = (const float*)d_in[10];
    const float* w1_1 = (const float*)d_in[11];
    const float* b1_1 = (const float*)d_in[12];
    const float* w0_2 = (const float*)d_in[13];
    const float* b0_2 = (const float*)d_in[14];
    const float* w1_2 = (const float*)d_in[15];
    const float* b1_2 = (const float*)d_in[16];
    const float* w_off = (const float*)d_in[17];
    const float* b_off = (const float*)d_in[18];

    float* out_verts = (float*)d_out;
    float* houtf = (float*)d_out + (size_t)3 * N_TOT;   // final h (f32)

    char* p = (char*)d_ws;
    unsigned* h1 = (unsigned*)p;   p += (size_t)(N_TOT + 1) * 64 * 4;  // 54 MB
    unsigned* h2 = (unsigned*)p;   p += (size_t)(N_TOT + 1) * 64 * 4;  // 54 MB
    int*    cnt  = (int*)p;        p += (size_t)N_TOT * 4;
    int*    adj  = (int*)p;        p += (size_t)N_TOT * CAP * 4;
    short*  Wt1  = (short*)p;      p += 128 * KD * 2;
    short*  Wt2  = (short*)p;      p += 128 * KD * 2;
    float4* hdA1 = (float4*)p;     p += 128 * 16;
    float4* hdB1 = (float4*)p;     p += 128 * 16;
    float4* hdA2 = (float4*)p;     p += 128 * 16;
    float4* hdB2 = (float4*)p;     p += 128 * 16;
    float4* nrm4 = (float4*)p;     p += (size_t)(N_TOT + 1) * 16;
    float4* SS   = (float4*)p;     p += (size_t)N_TOT * 16;

    hipMemsetAsync(cnt, 0, (size_t)N_TOT * 4, stream);
    hipMemsetAsync(h1 + (size_t)N_TOT * 64, 0, 256, stream);   // zero row
    hipMemsetAsync(h2 + (size_t)N_TOT * 64, 0, 256, stream);   // zero row
    fill_adj_kernel<<<(E_TOT + 255) / 256, 256, 0, stream>>>(edges, cnt, adj);
    pad_adj_kernel<<<(N_TOT + 255) / 256, 256, 0, stream>>>(cnt, adj);
    prep_nrm4_kernel<<<(N_TOT + 256) / 256, 256, 0, stream>>>(normals, nrm4);
    conv_w2_kernel<<<128, 256, 0, stream>>>(w0_1, b0_1, w1_1, b1_1, Wt1, hdA1, hdB1);
    conv_w2_kernel<<<128, 256, 0, stream>>>(w0_2, b0_2, w1_2, b1_2, Wt2, hdA2, hdB2);
    nsum_kernel<<<(N_TOT + 255) / 256, 256, 0, stream>>>(nrm4, cnt, adj, SS);

    // layer 0: analytic -> h1
    fused1_kernel<<<N_TOT / 16, 1024, 0, stream>>>(nrm4, SS, w0_0, b0_0, w1_0, b1_0, h1);
    // layer 1: gather Sum(h1) -> GEMM -> h2
    fused2_kernel<0><<<N_TOT / 16, 512, 0, stream>>>(h1, nrm4, SS, cnt, adj, Wt1, hdA1, hdB1,
                                                     h2, nullptr, nullptr, nullptr, nullptr,
                                                     nullptr, nullptr, nullptr);
    // layer 2 + epilogue: gather Sum(h2) -> GEMM -> h (f32) + verts
    fused2_kernel<1><<<N_TOT / 16, 512, 0, stream>>>(h2, nrm4, SS, cnt, adj, Wt2, hdA2, hdB2,
                                                     nullptr, verts, anchor_v, part_id,
                                                     w_off, b_off, houtf, out_verts);
}